// Round 1
// baseline (190.198 us; speedup 1.0000x reference)
//
#include <hip/hip_runtime.h>

// Tree-mux reduction: 25 levels over 2^25 virtual fp32 leaves
// (x[0..2^25-2] + trained_const_weight as the last leaf).
// mux(s,a,b) = 0.5*((1+s)*a + (1-s)*b) -> precompute cA=0.5(1+s), cB=0.5(1-s).

// k1: grid 4096 x 256. Thread = 32 contiguous leaves (levels 0..4 serial),
// wave butterfly shuffles (levels 5..10), cross-wave LDS (levels 11..12).
// Block covers 2^13 leaves -> one partial per block.
__global__ __launch_bounds__(256) void k1(const float* __restrict__ x,
                                          const float* __restrict__ cw,
                                          const float* __restrict__ w,
                                          float* __restrict__ part) {
    float cA[13], cB[13];
#pragma unroll
    for (int l = 0; l < 13; ++l) {
        float s = w[l];
        cA[l] = 0.5f * (1.0f + s);
        cB[l] = 0.5f * (1.0f - s);
    }
    const int t = threadIdx.x;
    const long long gt = (long long)blockIdx.x * 256 + t;
    const long long base = gt * 32;
    const long long LASTGT = (1LL << 25) / 32 - 1;  // owns virtual leaf 2^25-1

    float v[32];
    if (gt != LASTGT) {
#pragma unroll
        for (int j = 0; j < 8; ++j) {
            float4 f = *reinterpret_cast<const float4*>(x + base + j * 4);
            v[4 * j + 0] = f.x; v[4 * j + 1] = f.y;
            v[4 * j + 2] = f.z; v[4 * j + 3] = f.w;
        }
    } else {
#pragma unroll
        for (int j = 0; j < 7; ++j) {
            float4 f = *reinterpret_cast<const float4*>(x + base + j * 4);
            v[4 * j + 0] = f.x; v[4 * j + 1] = f.y;
            v[4 * j + 2] = f.z; v[4 * j + 3] = f.w;
        }
        v[28] = x[base + 28];
        v[29] = x[base + 29];
        v[30] = x[base + 30];
        v[31] = cw[0];  // virtual last leaf
    }

    // serial tree levels 0..4
#pragma unroll
    for (int l = 0, n = 32; n > 1; n >>= 1, ++l) {
#pragma unroll
        for (int i = 0; i < n / 2; ++i)
            v[i] = cA[l] * v[2 * i] + cB[l] * v[2 * i + 1];
    }
    float val = v[0];

    // butterfly shuffle levels 5..10 (64 lanes)
#pragma unroll
    for (int k = 0; k < 6; ++k) {
        const int l = 5 + k;
        float other = __shfl_xor(val, 1 << k, 64);
        bool upper = (t >> k) & 1;
        float a = upper ? other : val;
        float b = upper ? val : other;
        val = cA[l] * a + cB[l] * b;
    }

    // cross-wave levels 11..12
    __shared__ float lds[4];
    if ((t & 63) == 0) lds[t >> 6] = val;
    __syncthreads();
    if (t == 0) {
        float p01 = cA[11] * lds[0] + cB[11] * lds[1];
        float p23 = cA[11] * lds[2] + cB[11] * lds[3];
        part[blockIdx.x] = cA[12] * p01 + cB[12] * p23;
    }
}

// k2: 1 block x 256 threads over 4096 partials.
// serial 16/thread (levels 13..16), shuffle (17..22), LDS (23..24).
__global__ __launch_bounds__(256) void k2(const float* __restrict__ part,
                                          const float* __restrict__ w,
                                          float* __restrict__ out) {
    float cA[12], cB[12];
#pragma unroll
    for (int l = 0; l < 12; ++l) {
        float s = w[13 + l];
        cA[l] = 0.5f * (1.0f + s);
        cB[l] = 0.5f * (1.0f - s);
    }
    const int t = threadIdx.x;
    float v[16];
#pragma unroll
    for (int j = 0; j < 4; ++j) {
        float4 f = *reinterpret_cast<const float4*>(part + t * 16 + j * 4);
        v[4 * j + 0] = f.x; v[4 * j + 1] = f.y;
        v[4 * j + 2] = f.z; v[4 * j + 3] = f.w;
    }
#pragma unroll
    for (int l = 0, n = 16; n > 1; n >>= 1, ++l) {
#pragma unroll
        for (int i = 0; i < n / 2; ++i)
            v[i] = cA[l] * v[2 * i] + cB[l] * v[2 * i + 1];
    }
    float val = v[0];
#pragma unroll
    for (int k = 0; k < 6; ++k) {
        const int l = 4 + k;  // global level 17..22
        float other = __shfl_xor(val, 1 << k, 64);
        bool upper = (t >> k) & 1;
        float a = upper ? other : val;
        float b = upper ? val : other;
        val = cA[l] * a + cB[l] * b;
    }
    __shared__ float lds[4];
    if ((t & 63) == 0) lds[t >> 6] = val;
    __syncthreads();
    if (t == 0) {
        float p01 = cA[10] * lds[0] + cB[10] * lds[1];  // level 23
        float p23 = cA[10] * lds[2] + cB[10] * lds[3];
        out[0] = cA[11] * p01 + cB[11] * p23;           // level 24
    }
}

extern "C" void kernel_launch(void* const* d_in, const int* in_sizes, int n_in,
                              void* d_out, int out_size, void* d_ws, size_t ws_size,
                              hipStream_t stream) {
    const float* x  = (const float*)d_in[0];  // 2^25-1 floats
    const float* cw = (const float*)d_in[1];  // 1 float
    const float* w  = (const float*)d_in[2];  // 25 floats
    float* part = (float*)d_ws;               // 4096 floats = 16 KiB scratch

    k1<<<4096, 256, 0, stream>>>(x, cw, w, part);
    k2<<<1, 256, 0, stream>>>(part, w, (float*)d_out);
}

// Round 2
// 189.860 us; speedup vs baseline: 1.0018x; 1.0018x over previous
//
#include <hip/hip_runtime.h>

// Tree-mux reduction, coalesced formulation.
// root = sum_i x[i] * prod_l c(l, bit_l(i)), c(l,0)=0.5(1+w[l]), c(l,1)=0.5(1-w[l]).
// Leaf 2^25-1 is virtual = trained_const_weight.
//
// k1: grid 4096 x 256. Block covers 8192 leaves. Element index
// e = blk*8192 + iter*1024 + tid*4 -> lane-consecutive float4 (coalesced).
// float4 collapses levels 0..1; iter bits (of the level-2 node index) are
// levels 10..12 -> weighted accumulate; lane bits -> levels 2..7 (butterfly);
// wave bits -> levels 8..9 (LDS). One partial per block.
__global__ __launch_bounds__(256) void k1(const float* __restrict__ x,
                                          const float* __restrict__ cw,
                                          const float* __restrict__ w,
                                          float* __restrict__ part) {
    float cA[13], cB[13];
#pragma unroll
    for (int l = 0; l < 13; ++l) {
        float s = w[l];
        cA[l] = 0.5f * (1.0f + s);
        cB[l] = 0.5f * (1.0f - s);
    }
    // iteration coefficients: iter bit k <-> global level 10+k
    float ic[8];
#pragma unroll
    for (int i = 0; i < 8; ++i) {
        float c = ((i & 1) ? cB[10] : cA[10]);
        c *= ((i & 2) ? cB[11] : cA[11]);
        c *= ((i & 4) ? cB[12] : cA[12]);
        ic[i] = c;
    }
    const int t = threadIdx.x;
    const int b = blockIdx.x;
    const int blockBase = b * 8192;
    float acc = 0.0f;

#pragma unroll
    for (int it = 0; it < 8; ++it) {
        const int e = blockBase + it * 1024 + t * 4;
        float fx, fy, fz, fw;
        if (it == 7 && b == 4095) {              // uniform branch (compile-time it)
            if (t == 255) {                       // owns leaves 2^25-4 .. 2^25-1
                fx = x[e]; fy = x[e + 1]; fz = x[e + 2]; fw = cw[0];
            } else {
                float4 f = *reinterpret_cast<const float4*>(x + e);
                fx = f.x; fy = f.y; fz = f.z; fw = f.w;
            }
        } else {
            float4 f = *reinterpret_cast<const float4*>(x + e);
            fx = f.x; fy = f.y; fz = f.z; fw = f.w;
        }
        float p = cA[1] * (cA[0] * fx + cB[0] * fy) +
                  cB[1] * (cA[0] * fz + cB[0] * fw);
        acc = fmaf(ic[it], p, acc);
    }

    // butterfly shuffle: lane bit k <-> global level 2+k
    float val = acc;
#pragma unroll
    for (int k = 0; k < 6; ++k) {
        const int l = 2 + k;
        float other = __shfl_xor(val, 1 << k, 64);
        bool upper = (t >> k) & 1;
        float a = upper ? other : val;
        float bb = upper ? val : other;
        val = cA[l] * a + cB[l] * bb;
    }

    // wave bits: tid bit6 <-> level 8, bit7 <-> level 9
    __shared__ float lds[4];
    if ((t & 63) == 0) lds[t >> 6] = val;
    __syncthreads();
    if (t == 0) {
        float p01 = cA[8] * lds[0] + cB[8] * lds[1];
        float p23 = cA[8] * lds[2] + cB[8] * lds[3];
        part[b] = cA[9] * p01 + cB[9] * p23;
    }
}

// k2: 1 block x 256 threads over 4096 partials (levels 13..24), exact tree.
__global__ __launch_bounds__(256) void k2(const float* __restrict__ part,
                                          const float* __restrict__ w,
                                          float* __restrict__ out) {
    float cA[12], cB[12];
#pragma unroll
    for (int l = 0; l < 12; ++l) {
        float s = w[13 + l];
        cA[l] = 0.5f * (1.0f + s);
        cB[l] = 0.5f * (1.0f - s);
    }
    const int t = threadIdx.x;
    float v[16];
#pragma unroll
    for (int j = 0; j < 4; ++j) {
        float4 f = *reinterpret_cast<const float4*>(part + t * 16 + j * 4);
        v[4 * j + 0] = f.x; v[4 * j + 1] = f.y;
        v[4 * j + 2] = f.z; v[4 * j + 3] = f.w;
    }
#pragma unroll
    for (int l = 0, n = 16; n > 1; n >>= 1, ++l) {
#pragma unroll
        for (int i = 0; i < n / 2; ++i)
            v[i] = cA[l] * v[2 * i] + cB[l] * v[2 * i + 1];
    }
    float val = v[0];
#pragma unroll
    for (int k = 0; k < 6; ++k) {
        const int l = 4 + k;  // global level 17..22
        float other = __shfl_xor(val, 1 << k, 64);
        bool upper = (t >> k) & 1;
        float a = upper ? other : val;
        float bb = upper ? val : other;
        val = cA[l] * a + cB[l] * bb;
    }
    __shared__ float lds[4];
    if ((t & 63) == 0) lds[t >> 6] = val;
    __syncthreads();
    if (t == 0) {
        float p01 = cA[10] * lds[0] + cB[10] * lds[1];  // level 23
        float p23 = cA[10] * lds[2] + cB[10] * lds[3];
        out[0] = cA[11] * p01 + cB[11] * p23;           // level 24
    }
}

extern "C" void kernel_launch(void* const* d_in, const int* in_sizes, int n_in,
                              void* d_out, int out_size, void* d_ws, size_t ws_size,
                              hipStream_t stream) {
    const float* x  = (const float*)d_in[0];  // 2^25-1 floats
    const float* cw = (const float*)d_in[1];  // 1 float
    const float* w  = (const float*)d_in[2];  // 25 floats
    float* part = (float*)d_ws;               // 4096 floats = 16 KiB scratch

    k1<<<4096, 256, 0, stream>>>(x, cw, w, part);
    k2<<<1, 256, 0, stream>>>(part, w, (float*)d_out);
}